// Round 3
// baseline (477.346 us; speedup 1.0000x reference)
//
#include <hip/hip_runtime.h>

typedef unsigned int uint32;
typedef unsigned short ushort16;

#define DI __device__ __forceinline__

// ---- constants -------------------------------------------------------------
// B=2048, N_src=1, N_ngh=128, D_MODEL=FEAT=256, H=4, D_K=64, TEMP=8
#define BATCH 2048
#define NN    128
#define DM    256
#define NH    4
#define DK    64

// async global->LDS, 16B per lane; dest = wave-uniform base + lane*16,
// source = per-lane global address (pre-swizzled source pattern)
#define GLOAD_LDS16(g, s) \
  __builtin_amdgcn_global_load_lds( \
      (const __attribute__((address_space(1))) unsigned int*)(g), \
      (__attribute__((address_space(3))) unsigned int*)(s), 16, 0, 0)

#define WAIT_VMCNT(n) do { \
    asm volatile("s_waitcnt vmcnt(" #n ")" ::: "memory"); \
    __builtin_amdgcn_sched_barrier(0); \
  } while (0)

#define CFENCE() asm volatile("" ::: "memory")

DI float readl(float v, int lane) {
    return __uint_as_float(__builtin_amdgcn_readlane(__float_as_uint(v), lane));
}

// f32 -> bf16 (round to nearest even)
DI ushort16 f2bf(float f) {
    uint32 u = __float_as_uint(f);
    uint32 r = u + 0x7fffu + ((u >> 16) & 1u);
    return (ushort16)(r >> 16);
}

// unpack 8 bf16 (as uint4) -> 8 f32
DI void unpack8(const uint4 v, float f[8]) {
    f[0] = __uint_as_float(v.x << 16);
    f[1] = __uint_as_float(v.x & 0xffff0000u);
    f[2] = __uint_as_float(v.y << 16);
    f[3] = __uint_as_float(v.y & 0xffff0000u);
    f[4] = __uint_as_float(v.z << 16);
    f[5] = __uint_as_float(v.z & 0xffff0000u);
    f[6] = __uint_as_float(v.w << 16);
    f[7] = __uint_as_float(v.w & 0xffff0000u);
}

DI float dot8(const float* a, const float f[8], float acc) {
    acc = fmaf(a[0], f[0], acc);
    acc = fmaf(a[1], f[1], acc);
    acc = fmaf(a[2], f[2], acc);
    acc = fmaf(a[3], f[3], acc);
    acc = fmaf(a[4], f[4], acc);
    acc = fmaf(a[5], f[5], acc);
    acc = fmaf(a[6], f[6], acc);
    acc = fmaf(a[7], f[7], acc);
    return acc;
}

// ---- weight layout in d_ws bf16 area (element offsets) ---------------------
// WOFF_KS region holds wks TRANSPOSED: [c][r] = wks[r*256+c]
#define WOFF_QS  0
#define WOFF_KS  65536
#define WOFF_VS  131072
#define WOFF_FC  196608
#define WOFF_FC1 262144
#define WOFF_FC2 393216
// total 458752 bf16 elements

// ---- kernel 0: convert all weight matrices to bf16 in d_ws -----------------
__global__ __launch_bounds__(256) void prep_kernel(
    const float* __restrict__ wqs, const float* __restrict__ wks,
    const float* __restrict__ wvs, const float* __restrict__ fcw,
    const float* __restrict__ fc1w, const float* __restrict__ fc2w,
    ushort16* __restrict__ out)
{
    const int bid = blockIdx.x;
    const int t   = threadIdx.x;
    if (bid >= 64 && bid < 128) {
        // wks stored TRANSPOSED: out[WOFF_KS + c*256 + r] = bf16(wks[r*256+c])
        int base = (bid - 64) * 1024 + t * 4;
        float4 v = *(const float4*)(wks + base);
        int r = base >> 8, c = base & 255;
        out[WOFF_KS + (size_t)(c + 0) * 256 + r] = f2bf(v.x);
        out[WOFF_KS + (size_t)(c + 1) * 256 + r] = f2bf(v.y);
        out[WOFF_KS + (size_t)(c + 2) * 256 + r] = f2bf(v.z);
        out[WOFF_KS + (size_t)(c + 3) * 256 + r] = f2bf(v.w);
        return;
    }
    const float* srcp; size_t soff, doff;
    if (bid < 64)       { srcp = wqs;  soff = (size_t)bid * 1024;         doff = WOFF_QS;  }
    else if (bid < 192) { srcp = wvs;  soff = (size_t)(bid - 128) * 1024; doff = WOFF_VS;  }
    else if (bid < 256) { srcp = fcw;  soff = (size_t)(bid - 192) * 1024; doff = WOFF_FC;  }
    else if (bid < 384) { srcp = fc1w; soff = (size_t)(bid - 256) * 1024; doff = WOFF_FC1; }
    else                { srcp = fc2w; soff = (size_t)(bid - 384) * 1024; doff = WOFF_FC2; }
    float4 v = *(const float4*)(srcp + soff + t * 4);
    uint2 pk;
    pk.x = (uint32)f2bf(v.x) | ((uint32)f2bf(v.y) << 16);
    pk.y = (uint32)f2bf(v.z) | ((uint32)f2bf(v.w) << 16);
    *(uint2*)(out + doff + soff + t * 4) = pk;
}

// ---- kernel 1: fused q-proj + u + flash attention + pooled c ---------------
// grid 2048, block 512 (8 waves). Block b does everything for batch row b.
// Wave w owns seq rows [w*16, w*16+16), processed as 4 batches of 4 rows with
// a per-wave 2x4-row LDS double buffer + counted vmcnt pipeline (no barriers
// during the flash loop). LDS 73.3 KB -> 2 blocks/CU for cross-block overlap.
// Swizzle: LDS chunk position p of row r holds global 16B-chunk
// p ^ (((r&3)<<1) ^ ((p>>4)&3))  (involution; <=2-way banks on all reads).
#define USTRIDE 276

__global__ __launch_bounds__(512, 4) void attn_fused_kernel(
    const float* __restrict__ src, const float* __restrict__ seq,
    const int* __restrict__ mask, const ushort16* __restrict__ wbf,
    float* __restrict__ c, float* __restrict__ attn_out)
{
    __shared__ __align__(16) float sq_[16384];        // 64 KB: 8 waves x 2 bufs x 4 rows
    __shared__ __align__(16) float sU[NH * USTRIDE];  // u rows, padded
    __shared__ __align__(16) float sQ[256];           // q row
    __shared__ int   sMk[512];                        // mask rows [h][n]
    __shared__ __align__(16) float sM[8][4];          // per-wave per-head max
    __shared__ __align__(16) float sSg[8][4];         // per-wave per-head sum

    const int t = threadIdx.x;
    const int b = blockIdx.x;
    const int w = t >> 6, l = t & 63;
    const int rq = l >> 4;               // row-in-batch (0..3)
    const int myh = (l >> 2) & 3;        // head class
    const int kseg = l & 3;              // 64-elem k segment

    const float* sp = seq + (size_t)b * (NN * DM);
    float* wsl = &sq_[w * 2048];         // this wave's 8KB slice (2 x 1024 f32)

    // ---- mask rows into LDS (head-major tiling: row (4b+h) mod 2048) -------
    {
        int hh = t >> 7, n = t & 127;
        int mr = (4 * b + hh) & (BATCH - 1);
        sMk[t] = mask[(size_t)mr * NN + n];
    }

    // ---- q[t] = dot(src[b], wqs[t]) (threads 0..255) -----------------------
    if (t < 256) {
        float acc = 0.f;
        const ushort16* wrow = wbf + WOFF_QS + (size_t)t * DM;
        const float* srow = src + (size_t)b * DM;
        #pragma unroll 4
        for (int kc = 0; kc < DM; kc += 8) {
            uint4 w8 = *(const uint4*)(wrow + kc);
            float wf[8]; unpack8(w8, wf);
            float4 sa = *(const float4*)(srow + kc);
            float4 sb = *(const float4*)(srow + kc + 4);
            acc = fmaf(sa.x, wf[0], acc); acc = fmaf(sa.y, wf[1], acc);
            acc = fmaf(sa.z, wf[2], acc); acc = fmaf(sa.w, wf[3], acc);
            acc = fmaf(sb.x, wf[4], acc); acc = fmaf(sb.y, wf[5], acc);
            acc = fmaf(sb.z, wf[6], acc); acc = fmaf(sb.w, wf[7], acc);
        }
        sQ[t] = acc;
    }
    __syncthreads();

    // ---- u[h][cc] = dot(q[h*64:...], wksT[cc][h*64:...]) * 0.125 -----------
    // thread t -> outputs (h1, cc) and (h1+2, cc)
    {
        const int cc2 = t & 255;
        const int h1  = t >> 8;          // 0 or 1 (wave-uniform)
        float a0 = 0.f, a1 = 0.f;
        const ushort16* wr2 = wbf + WOFF_KS + (size_t)cc2 * DM;
        #pragma unroll 2
        for (int dc = 0; dc < DK; dc += 8) {
            uint4 wA = *(const uint4*)(wr2 + h1 * DK + dc);
            uint4 wB = *(const uint4*)(wr2 + (h1 + 2) * DK + dc);
            float fA[8], fB[8]; unpack8(wA, fA); unpack8(wB, fB);
            a0 = dot8(&sQ[h1 * DK + dc], fA, a0);
            a1 = dot8(&sQ[(h1 + 2) * DK + dc], fB, a1);
        }
        sU[h1 * USTRIDE + cc2]       = a0 * 0.125f;
        sU[(h1 + 2) * USTRIDE + cc2] = a1 * 0.125f;
    }
    __syncthreads();

    // ---- flash loop over 4 batches of 4 rows, per-wave dbuf ----------------
    float m0 = -1e30f, m1 = -1e30f, m2 = -1e30f, m3 = -1e30f;
    float sr0 = 0.f, sr1 = 0.f, sr2 = 0.f, sr3 = 0.f;
    float4 cc0 = {0,0,0,0}, cc1 = {0,0,0,0}, cc2v = {0,0,0,0}, cc3 = {0,0,0,0};
    float shist0 = 0.f, shist1 = 0.f, shist2 = 0.f, shist3 = 0.f;

    auto issue = [&](int kk, int bufoff) {
        CFENCE();
        #pragma unroll
        for (int i = 0; i < 4; ++i) {
            const int r = (w << 4) + kk * 4 + i;
            const int cp = l ^ (((r & 3) << 1) ^ rq);   // rq == (l>>4)&3
            GLOAD_LDS16(sp + r * 256 + cp * 4, wsl + bufoff + i * 256);
        }
    };

    auto process = [&](int kk, int bufoff, float& sh) {
        // scores: lane (rq, myh, kseg) partial-dots u[myh] . row rq
        const int r_my = (w << 4) + kk * 4 + rq;
        float s = 0.f;
        {
            const float* rowb = wsl + bufoff + rq * 256;
            const float* urow = &sU[myh * USTRIDE];
            const int sk = ((r_my & 3) << 1) ^ kseg;    // (c>>4)&3 == kseg here
            #pragma unroll
            for (int jj = 0; jj < 16; ++jj) {
                const int cidx = (kseg << 4) | jj;
                const int cp = cidx ^ sk;
                float4 sv = *(const float4*)(rowb + cp * 4);
                float4 uv = *(const float4*)(urow + cidx * 4);
                s = fmaf(uv.x, sv.x, s); s = fmaf(uv.y, sv.y, s);
                s = fmaf(uv.z, sv.z, s); s = fmaf(uv.w, sv.w, s);
            }
        }
        s += __shfl_xor(s, 1, 64);
        s += __shfl_xor(s, 2, 64);
        if (sMk[myh * 128 + r_my] != 0) s = -1e10f;
        sh = s;
        // batch max per head (reduce over rq = lane bits 4..5)
        float bmax = s;
        bmax = fmaxf(bmax, __shfl_xor(bmax, 16, 64));
        bmax = fmaxf(bmax, __shfl_xor(bmax, 32, 64));
        float bh0 = readl(bmax, 0), bh1 = readl(bmax, 4);
        float bh2 = readl(bmax, 8), bh3 = readl(bmax, 12);
        float n0 = fmaxf(m0, bh0), n1 = fmaxf(m1, bh1);
        float n2 = fmaxf(m2, bh2), n3 = fmaxf(m3, bh3);
        float f0 = __expf(m0 - n0), f1 = __expf(m1 - n1);
        float f2 = __expf(m2 - n2), f3 = __expf(m3 - n3);
        sr0 *= f0; sr1 *= f1; sr2 *= f2; sr3 *= f3;
        cc0.x *= f0; cc0.y *= f0; cc0.z *= f0; cc0.w *= f0;
        cc1.x *= f1; cc1.y *= f1; cc1.z *= f1; cc1.w *= f1;
        cc2v.x *= f2; cc2v.y *= f2; cc2v.z *= f2; cc2v.w *= f2;
        cc3.x *= f3; cc3.y *= f3; cc3.z *= f3; cc3.w *= f3;
        m0 = n0; m1 = n1; m2 = n2; m3 = n3;
        float nm = (myh == 0) ? n0 : (myh == 1) ? n1 : (myh == 2) ? n2 : n3;
        float e = __expf(s - nm);
        // pooling: lane owns col chunk l; E broadcast via readlane
        #pragma unroll
        for (int i = 0; i < 4; ++i) {
            const int r2 = (w << 4) + kk * 4 + i;
            const int cp = l ^ (((r2 & 3) << 1) ^ rq);
            float4 sv = *(const float4*)(wsl + bufoff + i * 256 + cp * 4);
            float e0 = readl(e, (i << 4) | 0);
            float e1 = readl(e, (i << 4) | 4);
            float e2 = readl(e, (i << 4) | 8);
            float e3 = readl(e, (i << 4) | 12);
            sr0 += e0; sr1 += e1; sr2 += e2; sr3 += e3;
            cc0.x = fmaf(e0, sv.x, cc0.x); cc0.y = fmaf(e0, sv.y, cc0.y);
            cc0.z = fmaf(e0, sv.z, cc0.z); cc0.w = fmaf(e0, sv.w, cc0.w);
            cc1.x = fmaf(e1, sv.x, cc1.x); cc1.y = fmaf(e1, sv.y, cc1.y);
            cc1.z = fmaf(e1, sv.z, cc1.z); cc1.w = fmaf(e1, sv.w, cc1.w);
            cc2v.x = fmaf(e2, sv.x, cc2v.x); cc2v.y = fmaf(e2, sv.y, cc2v.y);
            cc2v.z = fmaf(e2, sv.z, cc2v.z); cc2v.w = fmaf(e2, sv.w, cc2v.w);
            cc3.x = fmaf(e3, sv.x, cc3.x); cc3.y = fmaf(e3, sv.y, cc3.y);
            cc3.z = fmaf(e3, sv.z, cc3.z); cc3.w = fmaf(e3, sv.w, cc3.w);
        }
        CFENCE();
    };

    issue(0, 0);
    issue(1, 1024);
    WAIT_VMCNT(4);
    process(0, 0, shist0);
    issue(2, 0);
    WAIT_VMCNT(4);
    process(1, 1024, shist1);
    issue(3, 1024);
    WAIT_VMCNT(4);
    process(2, 0, shist2);
    WAIT_VMCNT(0);
    process(3, 1024, shist3);

    // ---- per-wave partials -> LDS (own slice, bufA area is dead) -----------
    CFENCE();
    *(float4*)(wsl + 0 * 256 + l * 4) = cc0;
    *(float4*)(wsl + 1 * 256 + l * 4) = cc1;
    *(float4*)(wsl + 2 * 256 + l * 4) = cc2v;
    *(float4*)(wsl + 3 * 256 + l * 4) = cc3;
    if (l == 0) {
        *(float4*)&sM[w][0]  = make_float4(m0, m1, m2, m3);
        *(float4*)&sSg[w][0] = make_float4(sr0, sr1, sr2, sr3);
    }
    __syncthreads();

    // ---- attn_out: lane's head class, rows k*4+rq ---------------------------
    {
        float Mh = sM[0][myh];
        #pragma unroll
        for (int w2 = 1; w2 < 8; ++w2) Mh = fmaxf(Mh, sM[w2][myh]);
        float Sh = 0.f;
        #pragma unroll
        for (int w2 = 0; w2 < 8; ++w2) Sh += sSg[w2][myh] * __expf(sM[w2][myh] - Mh);
        if (kseg == 0) {
            float inv = 1.f / Sh;
            size_t base = (size_t)b * (NH * NN) + myh * NN + (w << 4) + rq;
            attn_out[base + 0]  = __expf(shist0 - Mh) * inv;
            attn_out[base + 4]  = __expf(shist1 - Mh) * inv;
            attn_out[base + 8]  = __expf(shist2 - Mh) * inv;
            attn_out[base + 12] = __expf(shist3 - Mh) * inv;
        }
    }

    // ---- final pooled c: merge 8 wave partials ------------------------------
    #pragma unroll
    for (int rep = 0; rep < 2; ++rep) {
        int idx = t + rep * 512;
        int hh = idx >> 8, j = idx & 255;
        float M = sM[0][hh];
        #pragma unroll
        for (int w2 = 1; w2 < 8; ++w2) M = fmaxf(M, sM[w2][hh]);
        float S = 0.f, acc = 0.f;
        #pragma unroll
        for (int w2 = 0; w2 < 8; ++w2) {
            float sc = __expf(sM[w2][hh] - M);
            S   += sSg[w2][hh] * sc;
            acc += sq_[w2 * 2048 + hh * 256 + j] * sc;
        }
        c[(size_t)b * 1024 + idx] = acc / S;
    }
}

// ---- kernel 2: v-proj + fc + residual + LN + fc1(relu) + fc2 ---------------
// grid 256, block 256, 8 rows per block (best VALU amortization)
__global__ __launch_bounds__(256) void mlp_kernel(
    const float* __restrict__ c, const float* __restrict__ src,
    const ushort16* __restrict__ wbf,
    const float* __restrict__ fcb, const float* __restrict__ lng,
    const float* __restrict__ lnb, const float* __restrict__ fc1b,
    const float* __restrict__ fc2b, float* __restrict__ zout)
{
    __shared__ float sC[8][1024];   // pooled c rows (32 KB)
    __shared__ float sA[8][256];    // attention out rows
    __shared__ float sX[8][256];    // normalized x
    __shared__ float sS[8][256];    // src rows
    __shared__ float sH[8][256];    // relu(fc1) rows
    __shared__ float sRed[4][8][2]; // [wave][row][{sum, sumsq}]

    const int t  = threadIdx.x;
    const int b0 = blockIdx.x * 8;
    const int h  = t >> 6;          // head for stage A (uniform per wave)

    #pragma unroll
    for (int i = 0; i < 8; ++i)
        *(float4*)&sC[i][t * 4] = *(const float4*)&c[(size_t)(b0 + i) * 1024 + t * 4];
    #pragma unroll
    for (int r = 0; r < 8; ++r) sS[r][t] = src[(size_t)(b0 + r) * DM + t];
    __syncthreads();

    // stage A: out_attn[r][t] = dot(c[r][h*256 + :], wvs[t*256 + :])
    {
        float acc[8] = {0.f,0.f,0.f,0.f,0.f,0.f,0.f,0.f};
        const ushort16* wr = wbf + WOFF_VS + (size_t)t * DM;
        for (int kc = 0; kc < DM; kc += 8) {
            uint4 w8 = *(const uint4*)(wr + kc);
            float wf[8]; unpack8(w8, wf);
            #pragma unroll
            for (int r = 0; r < 8; ++r) acc[r] = dot8(&sC[r][h * 256 + kc], wf, acc[r]);
        }
        #pragma unroll
        for (int r = 0; r < 8; ++r) sA[r][t] = acc[r];
    }
    __syncthreads();

    // stage B: x = out_attn @ fcw^T + fcb + src ; then LayerNorm
    float xv[8];
    {
        float acc[8] = {0.f,0.f,0.f,0.f,0.f,0.f,0.f,0.f};
        const ushort16* wr = wbf + WOFF_FC + (size_t)t * DM;
        for (int kc = 0; kc < DM; kc += 8) {
            uint4 w8 = *(const uint4*)(wr + kc);
            float wf[8]; unpack8(w8, wf);
            #pragma unroll
            for (int r = 0; r < 8; ++r) acc[r] = dot8(&sA[r][kc], wf, acc[r]);
        }
        float bb = fcb[t];
        #pragma unroll
        for (int r = 0; r < 8; ++r) xv[r] = acc[r] + bb + sS[r][t];
    }
    {
        const int w = t >> 6, l = t & 63;
        #pragma unroll
        for (int r = 0; r < 8; ++r) {
            float vs = xv[r], vq = xv[r] * xv[r];
            #pragma unroll
            for (int o = 32; o > 0; o >>= 1) {
                vs += __shfl_xor(vs, o, 64);
                vq += __shfl_xor(vq, o, 64);
            }
            if (l == 0) { sRed[w][r][0] = vs; sRed[w][r][1] = vq; }
        }
        __syncthreads();
        float g = lng[t], bb = lnb[t];
        #pragma unroll
        for (int r = 0; r < 8; ++r) {
            float S = sRed[0][r][0] + sRed[1][r][0] + sRed[2][r][0] + sRed[3][r][0];
            float Q = sRed[0][r][1] + sRed[1][r][1] + sRed[2][r][1] + sRed[3][r][1];
            float mu  = S * (1.f / 256.f);
            float var = Q * (1.f / 256.f) - mu * mu;
            float rs  = rsqrtf(var + 1e-5f);
            sX[r][t] = (xv[r] - mu) * rs * g + bb;
        }
    }
    __syncthreads();

    // stage C: h1 = relu([x | src] @ fc1w^T + fc1b)
    {
        float acc[8] = {0.f,0.f,0.f,0.f,0.f,0.f,0.f,0.f};
        const ushort16* wr = wbf + WOFF_FC1 + (size_t)t * 512;
        for (int kc = 0; kc < 256; kc += 8) {
            uint4 w8 = *(const uint4*)(wr + kc);
            float wf[8]; unpack8(w8, wf);
            #pragma unroll
            for (int r = 0; r < 8; ++r) acc[r] = dot8(&sX[r][kc], wf, acc[r]);
        }
        for (int kc = 0; kc < 256; kc += 8) {
            uint4 w8 = *(const uint4*)(wr + 256 + kc);
            float wf[8]; unpack8(w8, wf);
            #pragma unroll
            for (int r = 0; r < 8; ++r) acc[r] = dot8(&sS[r][kc], wf, acc[r]);
        }
        float bb = fc1b[t];
        #pragma unroll
        for (int r = 0; r < 8; ++r) sH[r][t] = fmaxf(acc[r] + bb, 0.f);
    }
    __syncthreads();

    // stage D: z = h1 @ fc2w^T + fc2b
    {
        float acc[8] = {0.f,0.f,0.f,0.f,0.f,0.f,0.f,0.f};
        const ushort16* wr = wbf + WOFF_FC2 + (size_t)t * DM;
        for (int kc = 0; kc < DM; kc += 8) {
            uint4 w8 = *(const uint4*)(wr + kc);
            float wf[8]; unpack8(w8, wf);
            #pragma unroll
            for (int r = 0; r < 8; ++r) acc[r] = dot8(&sH[r][kc], wf, acc[r]);
        }
        float bb = fc2b[t];
        #pragma unroll
        for (int r = 0; r < 8; ++r)
            zout[(size_t)(b0 + r) * DM + t] = acc[r] + bb;
    }
}

// ---- launch ----------------------------------------------------------------
extern "C" void kernel_launch(void* const* d_in, const int* in_sizes, int n_in,
                              void* d_out, int out_size, void* d_ws, size_t ws_size,
                              hipStream_t stream)
{
    const float* src  = (const float*)d_in[0];
    const float* seq  = (const float*)d_in[1];
    const int*   mask = (const int*)d_in[2];
    const float* wqs  = (const float*)d_in[3];
    const float* wks  = (const float*)d_in[4];
    const float* wvs  = (const float*)d_in[5];
    const float* fcw  = (const float*)d_in[6];
    const float* fcb  = (const float*)d_in[7];
    const float* lng  = (const float*)d_in[8];
    const float* lnb  = (const float*)d_in[9];
    const float* fc1w = (const float*)d_in[10];
    const float* fc1b = (const float*)d_in[11];
    const float* fc2w = (const float*)d_in[12];
    const float* fc2b = (const float*)d_in[13];

    float* zout     = (float*)d_out;
    float* attn_out = zout + (size_t)BATCH * DM;      // z first, then attn

    float* cbuf = (float*)d_ws;                       // 2048*1024 f32 = 8 MB
    ushort16* wbf = (ushort16*)(cbuf + (size_t)BATCH * 1024);  // 458752 bf16

    prep_kernel<<<448, 256, 0, stream>>>(wqs, wks, wvs, fcw, fc1w, fc2w, wbf);
    attn_fused_kernel<<<BATCH, 512, 0, stream>>>(src, seq, mask, wbf,
                                                 cbuf, attn_out);
    mlp_kernel<<<256, 256, 0, stream>>>(cbuf, src, wbf, fcb, lng, lnb,
                                        fc1b, fc2b, zout);
}